// Round 5
// baseline (352.522 us; speedup 1.0000x reference)
//
#include <hip/hip_runtime.h>

typedef unsigned short ushort_t;
typedef unsigned int u32;
typedef short short8 __attribute__((ext_vector_type(8)));
typedef short short4_t __attribute__((ext_vector_type(4)));
typedef float f32x4 __attribute__((ext_vector_type(4)));
typedef float f32x16 __attribute__((ext_vector_type(16)));

#define NTOK 4096
#define NCOLS 65536
#define CIN 256

__device__ __forceinline__ float b2f(ushort_t u) {
    union { unsigned int i; float f; } v; v.i = ((unsigned int)u) << 16; return v.f;
}
__device__ __forceinline__ ushort_t f2b(float f) {
    union { float f; unsigned int i; } v; v.f = f;
    unsigned int r = v.i + 0x7FFFu + ((v.i >> 16) & 1u);   // RNE
    return (ushort_t)(r >> 16);
}

__device__ __forceinline__ void gl_lds16(const ushort_t* g, ushort_t* l) {
    __builtin_amdgcn_global_load_lds(
        (const __attribute__((address_space(1))) u32*)(const void*)g,
        (__attribute__((address_space(3))) u32*)(void*)l,
        16, 0, 0);
}

// ---------------------------------------------------------------------------
// weights fp32 -> bf16; zero ctx accumulator (512 KB) + qsums (16 KB) in d_out
__global__ __launch_bounds__(256) void cvt_w(const float* __restrict__ wq,
                                             const float* __restrict__ wp,
                                             ushort_t* __restrict__ wqb,
                                             ushort_t* __restrict__ wpb,
                                             float* __restrict__ scz) {
    int i = blockIdx.x * 256 + threadIdx.x;      // 0 .. 262143
    if (i < 768 * 256) wqb[i] = f2b(wq[i]);
    else               wpb[i - 768 * 256] = f2b(wp[i - 768 * 256]);
    if (i < 131072 + 4096) scz[i] = 0.f;
}

// ---------------------------------------------------------------------------
// x fp32 [16][256][4096] -> xt bf16 [65536][256] (token-major)
__global__ __launch_bounds__(256) void transpose_x(const float* __restrict__ x,
                                                   ushort_t* __restrict__ xt) {
    int tl = threadIdx.x & 63, cg = threadIdx.x >> 6;
    int g = blockIdx.x * 64 + tl;
    int b = g >> 12, n = g & 4095;
    const float* src = x + (size_t)b * (CIN * NTOK) + n;
    ushort_t* dst = xt + (size_t)g * CIN + cg * 64;
    for (int j8 = 0; j8 < 8; j8++) {
        short8 vr;
#pragma unroll
        for (int j = 0; j < 8; j++)
            vr[j] = (short)f2b(src[(size_t)(cg * 64 + j8 * 8 + j) * NTOK]);
        *(short8*)(dst + j8 * 8) = vr;
    }
}

// ---------------------------------------------------------------------------
// 128x128-tile GEMM + fused BN (+softmax) epilogue.  A-operand = tokens (so the
// C/D reg dim = 4 consecutive tokens -> vector stores).  W [M][256], Xc [65536][256].
// mode 0 (qkv): y<2 -> Q: store exp(BN) bf16 + atomic row-sums; y in {2,3} -> K:
//   per-token softmax over each 32-chan head; y>=4 -> V: plain BN bf16.
// mode 1 (proj): fp32 out[b][m][n], float4 stores.
__global__ __launch_bounds__(256) void gemm128(const ushort_t* __restrict__ W,
                                               const ushort_t* __restrict__ Xc,
                                               const float* __restrict__ gamma,
                                               const float* __restrict__ beta,
                                               const float* __restrict__ mean,
                                               const float* __restrict__ var,
                                               ushort_t* __restrict__ out_b,
                                               float* __restrict__ out_f,
                                               float* __restrict__ qsums, int mode) {
    __shared__ __align__(16) ushort_t lA[128 * 32];   // W rows (chans)
    __shared__ __align__(16) ushort_t lB[128 * 32];   // Xc rows (tokens)
    int tid = threadIdx.x;
    int wave = tid >> 6, lane = tid & 63;
    int l15 = lane & 15, q = lane >> 4;
    int th = wave >> 1, ch = wave & 1;               // token-half / chan-half
    int m0 = blockIdx.y * 128, colb = blockIdx.x * 128;

    f32x4 acc[4][4];                                  // [ti][ci]
#pragma unroll
    for (int i = 0; i < 4; i++)
#pragma unroll
        for (int j = 0; j < 4; j++)
#pragma unroll
            for (int r = 0; r < 4; r++) acc[i][j][r] = 0.f;

    const ushort_t* gA0 = W  + (size_t)(m0 +      (tid >> 2)) * CIN + (tid & 3) * 8;
    const ushort_t* gA1 = W  + (size_t)(m0 + 64 + (tid >> 2)) * CIN + (tid & 3) * 8;
    const ushort_t* gB0 = Xc + (size_t)(colb +      (tid >> 2)) * CIN + (tid & 3) * 8;
    const ushort_t* gB1 = Xc + (size_t)(colb + 64 + (tid >> 2)) * CIN + (tid & 3) * 8;
    ushort_t* la0 = &lA[tid * 8];
    ushort_t* la1 = &lA[2048 + tid * 8];
    ushort_t* lb0 = &lB[tid * 8];
    ushort_t* lb1 = &lB[2048 + tid * 8];

    for (int k0 = 0; k0 < CIN; k0 += 32) {
        gl_lds16(gA0 + k0, la0);
        gl_lds16(gA1 + k0, la1);
        gl_lds16(gB0 + k0, lb0);
        gl_lds16(gB1 + k0, lb1);
        __syncthreads();
        short8 af[4], bf[4];
#pragma unroll
        for (int i = 0; i < 4; i++) {
            af[i] = *(const short8*)&lB[(th * 64 + i * 16 + l15) * 32 + q * 8]; // tokens
            bf[i] = *(const short8*)&lA[(ch * 64 + i * 16 + l15) * 32 + q * 8]; // chans
        }
#pragma unroll
        for (int ti = 0; ti < 4; ti++)
#pragma unroll
            for (int ci = 0; ci < 4; ci++)
                acc[ti][ci] = __builtin_amdgcn_mfma_f32_16x16x32_bf16(af[ti], bf[ci],
                                                                      acc[ti][ci], 0, 0, 0);
        __syncthreads();
    }

    // BN per chan (ci, l15)
    float s[4], sh[4];
    int mch[4];
#pragma unroll
    for (int ci = 0; ci < 4; ci++) {
        int m = m0 + ch * 64 + ci * 16 + l15;
        mch[ci] = m;
        s[ci] = gamma[m] * rsqrtf(var[m] + 1e-5f);
        sh[ci] = beta[m] - mean[m] * s[ci];
    }
    int tb = colb + th * 64;                         // + ti*16 + q*4 (+r)
    int y = blockIdx.y;

    if (mode == 1) {                                 // proj -> fp32 [b][m][n]
        int bb = colb >> 12;
#pragma unroll
        for (int ti = 0; ti < 4; ti++) {
            int n0 = ((tb + ti * 16 + q * 4) & 4095);
#pragma unroll
            for (int ci = 0; ci < 4; ci++) {
                f32x4 v;
#pragma unroll
                for (int r = 0; r < 4; r++) v[r] = acc[ti][ci][r] * s[ci] + sh[ci];
                *(f32x4*)(out_f + (size_t)bb * (CIN * NTOK) + (size_t)mch[ci] * NTOK + n0) = v;
            }
        }
    } else if (y >= 4) {                             // V: plain BN bf16
#pragma unroll
        for (int ti = 0; ti < 4; ti++) {
            int t0 = tb + ti * 16 + q * 4;
#pragma unroll
            for (int ci = 0; ci < 4; ci++) {
                short4_t pk;
#pragma unroll
                for (int r = 0; r < 4; r++) pk[r] = (short)f2b(acc[ti][ci][r] * s[ci] + sh[ci]);
                *(short4_t*)(out_b + (size_t)mch[ci] * NCOLS + t0) = pk;
            }
        }
    } else if (y >= 2) {                             // K: softmax over 32-chan head
#pragma unroll
        for (int ti = 0; ti < 4; ti++) {
            int t0 = tb + ti * 16 + q * 4;
#pragma unroll
            for (int hp = 0; hp < 2; hp++) {
                int c0 = 2 * hp, c1 = 2 * hp + 1;
                float e0[4], e1[4];
                short4_t p0, p1;
#pragma unroll
                for (int r = 0; r < 4; r++) {
                    e0[r] = __expf(acc[ti][c0][r] * s[c0] + sh[c0]);
                    e1[r] = __expf(acc[ti][c1][r] * s[c1] + sh[c1]);
                    float t = e0[r] + e1[r];
                    t += __shfl_xor(t, 1);
                    t += __shfl_xor(t, 2);
                    t += __shfl_xor(t, 4);
                    t += __shfl_xor(t, 8);
                    float inv = 1.f / t;
                    p0[r] = (short)f2b(e0[r] * inv);
                    p1[r] = (short)f2b(e1[r] * inv);
                }
                *(short4_t*)(out_b + (size_t)mch[c0] * NCOLS + t0) = p0;
                *(short4_t*)(out_b + (size_t)mch[c1] * NCOLS + t0) = p1;
            }
        }
    } else {                                         // Q: store exp(BN), atomic row-sums
        int bb = colb >> 12;
        float part[4] = {0.f, 0.f, 0.f, 0.f};
#pragma unroll
        for (int ti = 0; ti < 4; ti++) {
            int t0 = tb + ti * 16 + q * 4;
#pragma unroll
            for (int ci = 0; ci < 4; ci++) {
                short4_t pk;
#pragma unroll
                for (int r = 0; r < 4; r++) {
                    float e = __expf(acc[ti][ci][r] * s[ci] + sh[ci]);
                    ushort_t hv = f2b(e);
                    pk[r] = (short)hv;
                    part[ci] += b2f(hv);             // sum the rounded value (consistency)
                }
                *(short4_t*)(out_b + (size_t)mch[ci] * NCOLS + t0) = pk;
            }
        }
#pragma unroll
        for (int ci = 0; ci < 4; ci++) {
            float p = part[ci];
            p += __shfl_xor(p, 16);
            p += __shfl_xor(p, 32);
            if (q == 0) atomicAdd(qsums + mch[ci] * 16 + bb, p);
        }
    }
}

// ---------------------------------------------------------------------------
// ctx[bh][d][e] += sum_n ksm[d][n] * v[e][n]   (split-K, 8 slices x 512 tokens)
__global__ __launch_bounds__(256) void ctx_ker(const ushort_t* __restrict__ qkv,
                                               float* __restrict__ ctxbuf) {
    int sl = blockIdx.x, bh = blockIdx.y;
    int b = bh >> 3, h = bh & 7;
    int tid = threadIdx.x, wave = tid >> 6, lane = tid & 63;
    int l31 = lane & 31, l5 = lane >> 5;
    int col0 = b * NTOK + sl * 512 + wave * 128;
    const ushort_t* krow = qkv + (size_t)(256 + h * 32 + l31) * NCOLS + col0 + l5 * 8;
    const ushort_t* vrow = qkv + (size_t)(512 + h * 32 + l31) * NCOLS + col0 + l5 * 8;
    f32x16 acc;
#pragma unroll
    for (int i = 0; i < 16; i++) acc[i] = 0.f;
#pragma unroll
    for (int st = 0; st < 8; st++) {
        short8 af = *(const short8*)(krow + st * 16);
        short8 bf = *(const short8*)(vrow + st * 16);
        acc = __builtin_amdgcn_mfma_f32_32x32x16_bf16(af, bf, acc, 0, 0, 0);
    }
    __shared__ float red[4][1024];
#pragma unroll
    for (int r = 0; r < 16; r++) {
        int d = (r & 3) + 8 * (r >> 2) + 4 * l5;
        red[wave][d * 32 + l31] = acc[r];
    }
    __syncthreads();
    int i0 = tid * 4;
#pragma unroll
    for (int i = 0; i < 4; i++) {
        int idx = i0 + i;
        float v = red[0][idx] + red[1][idx] + red[2][idx] + red[3][idx];
        atomicAdd(ctxbuf + (size_t)bh * 1024 + idx, v);
    }
}

// ---------------------------------------------------------------------------
// out[e][n] = sum_d (ctx[d][e]/S[d]) * qexp[d][n]  -> attT[token][256]
__global__ __launch_bounds__(256) void out_ker(const ushort_t* __restrict__ qkv,
                                               const float* __restrict__ ctxbuf,
                                               const float* __restrict__ qsums,
                                               ushort_t* __restrict__ attT) {
    int sl = blockIdx.x, bh = blockIdx.y;
    int b = bh >> 3, h = bh & 7;
    int tid = threadIdx.x, wave = tid >> 6, lane = tid & 63;
    int l31 = lane & 31, l5 = lane >> 5;
    __shared__ __align__(16) ushort_t ctxT[32 * 40];
    __shared__ __align__(16) ushort_t qT[256 * 40];
    __shared__ __align__(16) ushort_t obuf[4][32 * 40];

#pragma unroll
    for (int i = 0; i < 4; i++) {
        int idx = tid * 4 + i;
        int d = idx >> 5, e = idx & 31;
        float sc = qsums[(h * 32 + d) * 16 + b];
        ctxT[e * 40 + d] = f2b(ctxbuf[(size_t)bh * 1024 + idx] / sc);
    }
    __syncthreads();
    short8 a0 = *(const short8*)(ctxT + l31 * 40 + l5 * 8);
    short8 a1 = *(const short8*)(ctxT + l31 * 40 + 16 + l5 * 8);

    const ushort_t* qbase = qkv + (size_t)(h * 32) * NCOLS;
    int segbase = b * NTOK + sl * 512;

    for (int nc = 0; nc < 2; nc++) {
        int gcol0 = segbase + nc * 256;
        int d = tid & 31, t8 = (tid >> 5) * 8;
#pragma unroll
        for (int jj = 0; jj < 4; jj++) {
            int tok8 = jj * 64 + t8;
            short8 pk = *(const short8*)(qbase + (size_t)d * NCOLS + gcol0 + tok8);
#pragma unroll
            for (int j = 0; j < 8; j++) qT[(tok8 + j) * 40 + d] = (ushort_t)pk[j];
        }
        __syncthreads();
#pragma unroll
        for (int ti = 0; ti < 2; ti++) {
            int tok0 = (wave + ti * 4) * 32;
            f32x16 acc;
#pragma unroll
            for (int i = 0; i < 16; i++) acc[i] = 0.f;
            short8 b0 = *(const short8*)(qT + (size_t)(tok0 + l31) * 40 + l5 * 8);
            short8 b1 = *(const short8*)(qT + (size_t)(tok0 + l31) * 40 + 16 + l5 * 8);
            acc = __builtin_amdgcn_mfma_f32_32x32x16_bf16(a0, b0, acc, 0, 0, 0);
            acc = __builtin_amdgcn_mfma_f32_32x32x16_bf16(a1, b1, acc, 0, 0, 0);
#pragma unroll
            for (int r = 0; r < 16; r++) {
                int e = (r & 3) + 8 * (r >> 2) + 4 * l5;
                obuf[wave][l31 * 40 + e] = f2b(acc[r]);
            }
            __syncthreads();
            {
                int tok = lane >> 1, half = lane & 1;
                const ushort_t* srcp = &obuf[wave][tok * 40 + half * 16];
                short8 r0 = *(const short8*)srcp;
                short8 r1 = *(const short8*)(srcp + 8);
                size_t g = (size_t)(gcol0 + tok0 + tok) * 256 + h * 32 + half * 16;
                *(short8*)(attT + g) = r0;
                *(short8*)(attT + g + 8) = r1;
            }
            __syncthreads();
        }
        __syncthreads();
    }
}

// ---------------------------------------------------------------------------
extern "C" void kernel_launch(void* const* d_in, const int* in_sizes, int n_in,
                              void* d_out, int out_size, void* d_ws, size_t ws_size,
                              hipStream_t stream) {
    const float* x          = (const float*)d_in[0];
    const float* qkv_w      = (const float*)d_in[1];
    const float* qkv_gamma  = (const float*)d_in[2];
    const float* qkv_beta   = (const float*)d_in[3];
    const float* qkv_mean   = (const float*)d_in[4];
    const float* qkv_var    = (const float*)d_in[5];
    const float* proj_w     = (const float*)d_in[6];
    const float* proj_gamma = (const float*)d_in[7];
    const float* proj_beta  = (const float*)d_in[8];
    const float* proj_mean  = (const float*)d_in[9];
    const float* proj_var   = (const float*)d_in[10];

    ushort_t* wqb = (ushort_t*)d_ws;                 // 393,216 B
    ushort_t* wpb = wqb + 768 * 256;                 // 131,072 B
    ushort_t* xt  = wpb + 256 * 256;                 // 33.5 MB (also attT later)
    ushort_t* qkv = xt + (size_t)NCOLS * CIN;        // 100.7 MB
    float* out    = (float*)d_out;
    float* ctxbuf = (float*)d_out;                   // 512 KB scratch in d_out
    float* qsums  = ctxbuf + 131072;                 // 16 KB scratch in d_out

    cvt_w<<<1024, 256, 0, stream>>>(qkv_w, proj_w, wqb, wpb, ctxbuf);
    transpose_x<<<1024, 256, 0, stream>>>(x, xt);
    gemm128<<<dim3(512, 6), 256, 0, stream>>>(wqb, xt, qkv_gamma, qkv_beta,
                                              qkv_mean, qkv_var, qkv, nullptr,
                                              qsums, 0);
    ctx_ker<<<dim3(8, 128), 256, 0, stream>>>(qkv, ctxbuf);
    out_ker<<<dim3(8, 128), 256, 0, stream>>>(qkv, ctxbuf, qsums, xt);
    gemm128<<<dim3(512, 2), 256, 0, stream>>>(wpb, xt, proj_gamma, proj_beta,
                                              proj_mean, proj_var, nullptr, out,
                                              qsums, 1);
}

// Round 6
// 296.375 us; speedup vs baseline: 1.1894x; 1.1894x over previous
//
#include <hip/hip_runtime.h>

typedef unsigned short ushort_t;
typedef unsigned int u32;
typedef short short8 __attribute__((ext_vector_type(8)));
typedef short short4_t __attribute__((ext_vector_type(4)));
typedef float f32x4 __attribute__((ext_vector_type(4)));
typedef float f32x16 __attribute__((ext_vector_type(16)));

#define NTOK 4096
#define NCOLS 65536
#define CIN 256

__device__ __forceinline__ float b2f(ushort_t u) {
    union { unsigned int i; float f; } v; v.i = ((unsigned int)u) << 16; return v.f;
}
__device__ __forceinline__ ushort_t f2b(float f) {
    union { float f; unsigned int i; } v; v.f = f;
    unsigned int r = v.i + 0x7FFFu + ((v.i >> 16) & 1u);   // RNE
    return (ushort_t)(r >> 16);
}

__device__ __forceinline__ void gl_lds16(const ushort_t* g, ushort_t* l) {
    __builtin_amdgcn_global_load_lds(
        (const __attribute__((address_space(1))) u32*)(const void*)g,
        (__attribute__((address_space(3))) u32*)(void*)l,
        16, 0, 0);
}

// ---------------------------------------------------------------------------
// weights fp32 -> bf16; zero ctx accumulator (512 KB) in d_out
__global__ __launch_bounds__(256) void cvt_w(const float* __restrict__ wq,
                                             const float* __restrict__ wp,
                                             ushort_t* __restrict__ wqb,
                                             ushort_t* __restrict__ wpb,
                                             float* __restrict__ scz) {
    int i = blockIdx.x * 256 + threadIdx.x;      // 0 .. 262143
    if (i < 768 * 256) wqb[i] = f2b(wq[i]);
    else               wpb[i - 768 * 256] = f2b(wp[i - 768 * 256]);
    if (i < 131072) scz[i] = 0.f;
}

// ---------------------------------------------------------------------------
// x fp32 [16][256][4096] -> xt bf16 [65536][256], LDS-tiled (both sides coalesced)
__global__ __launch_bounds__(256) void transpose_x(const float* __restrict__ x,
                                                   ushort_t* __restrict__ xt) {
    __shared__ ushort_t lds[64 * 264];           // 33,792 B; 528B rows (16B-aligned)
    int tid = threadIdx.x;
    int g0 = blockIdx.x * 64;                    // 64 tokens per block
    int b = g0 >> 12, n0 = g0 & 4095;
    const float* src = x + (size_t)b * (CIN * NTOK);
    int tn = tid & 63, cg = tid >> 6;
    for (int c4 = 0; c4 < 64; c4++) {
        int c = c4 * 4 + cg;
        lds[tn * 264 + c] = f2b(src[(size_t)c * NTOK + n0 + tn]);
    }
    __syncthreads();
    int tok = tid >> 2, c8 = (tid & 3) * 8;
    ushort_t* dst = xt + (size_t)(g0 + tok) * CIN + c8;
#pragma unroll
    for (int j = 0; j < 8; j++)
        *(short8*)(dst + j * 32) = *(const short8*)&lds[tok * 264 + c8 + j * 32];
}

// ---------------------------------------------------------------------------
// R4-proven 128x128-tile GEMM + plain BN epilogue (thin — R5 lesson).
// mode 0: out_b[m*65536 + col] bf16   |   mode 1: out_f[b][m][n] fp32
__global__ __launch_bounds__(256) void gemm128(const ushort_t* __restrict__ W,
                                               const ushort_t* __restrict__ Xc,
                                               const float* __restrict__ gamma,
                                               const float* __restrict__ beta,
                                               const float* __restrict__ mean,
                                               const float* __restrict__ var,
                                               ushort_t* __restrict__ out_b,
                                               float* __restrict__ out_f, int mode) {
    __shared__ __align__(16) ushort_t lA[128 * 32];
    __shared__ __align__(16) ushort_t lB[128 * 32];
    int tid = threadIdx.x;
    int wave = tid >> 6, lane = tid & 63;
    int l15 = lane & 15, q = lane >> 4;
    int mh = wave >> 1, nh = wave & 1;
    int m0 = blockIdx.y * 128, colb = blockIdx.x * 128;

    f32x4 acc[4][4];
#pragma unroll
    for (int i = 0; i < 4; i++)
#pragma unroll
        for (int j = 0; j < 4; j++)
#pragma unroll
            for (int r = 0; r < 4; r++) acc[i][j][r] = 0.f;

    const ushort_t* gA0 = W  + (size_t)(m0 +      (tid >> 2)) * CIN + (tid & 3) * 8;
    const ushort_t* gA1 = W  + (size_t)(m0 + 64 + (tid >> 2)) * CIN + (tid & 3) * 8;
    const ushort_t* gB0 = Xc + (size_t)(colb +      (tid >> 2)) * CIN + (tid & 3) * 8;
    const ushort_t* gB1 = Xc + (size_t)(colb + 64 + (tid >> 2)) * CIN + (tid & 3) * 8;
    ushort_t* la0 = &lA[tid * 8];
    ushort_t* la1 = &lA[2048 + tid * 8];
    ushort_t* lb0 = &lB[tid * 8];
    ushort_t* lb1 = &lB[2048 + tid * 8];

    for (int k0 = 0; k0 < CIN; k0 += 32) {
        gl_lds16(gA0 + k0, la0);
        gl_lds16(gA1 + k0, la1);
        gl_lds16(gB0 + k0, lb0);
        gl_lds16(gB1 + k0, lb1);
        __syncthreads();
        short8 af[4], bf[4];
#pragma unroll
        for (int i = 0; i < 4; i++) {
            af[i] = *(const short8*)&lA[(mh * 64 + i * 16 + l15) * 32 + q * 8];
            bf[i] = *(const short8*)&lB[(nh * 64 + i * 16 + l15) * 32 + q * 8];
        }
#pragma unroll
        for (int mi = 0; mi < 4; mi++)
#pragma unroll
            for (int ni = 0; ni < 4; ni++)
                acc[mi][ni] = __builtin_amdgcn_mfma_f32_16x16x32_bf16(af[mi], bf[ni],
                                                                      acc[mi][ni], 0, 0, 0);
        __syncthreads();
    }

    int col_l = colb + nh * 64 + l15;
#pragma unroll
    for (int mi = 0; mi < 4; mi++) {
#pragma unroll
        for (int r = 0; r < 4; r++) {
            int m = m0 + mh * 64 + mi * 16 + q * 4 + r;
            float sc = gamma[m] * rsqrtf(var[m] + 1e-5f);
            float sh = beta[m] - mean[m] * sc;
#pragma unroll
            for (int ni = 0; ni < 4; ni++) {
                float val = acc[mi][ni][r] * sc + sh;
                int col = col_l + ni * 16;
                if (mode == 0) {
                    out_b[(size_t)m * NCOLS + col] = f2b(val);
                } else {
                    int bb = col >> 12, n = col & 4095;
                    out_f[(size_t)bb * (CIN * NTOK) + (size_t)m * NTOK + n] = val;
                }
            }
        }
    }
}

// ---------------------------------------------------------------------------
// S_q[c][b] = sum_n exp(q_raw[c][b*4096+n])   (one wave per (c,b) row)
__global__ __launch_bounds__(256) void qsum_ker(const ushort_t* __restrict__ qkv,
                                                float* __restrict__ qsums) {
    int tid = threadIdx.x, wave = tid >> 6, lane = tid & 63;
    int rid = blockIdx.x * 4 + wave;             // 0..4095
    int c = rid >> 4, b = rid & 15;
    const ushort_t* row = qkv + (size_t)c * NCOLS + b * NTOK;
    float s = 0.f;
#pragma unroll
    for (int j = 0; j < 8; j++) {
        short8 pk = *(const short8*)(row + j * 512 + lane * 8);
#pragma unroll
        for (int i = 0; i < 8; i++) s += __expf(b2f((ushort_t)pk[i]));
    }
    for (int off = 1; off < 64; off <<= 1) s += __shfl_xor(s, off);
    if (lane == 0) qsums[c * 16 + b] = s;
}

// ---------------------------------------------------------------------------
// ctx[bh][d][e] += sum_n ksm[d][n]*v[e][n]; k-softmax fused (d = lane dim l31)
__global__ __launch_bounds__(256) void ctx_ker(const ushort_t* __restrict__ qkv,
                                               float* __restrict__ ctxbuf) {
    int sl = blockIdx.x, bh = blockIdx.y;
    int b = bh >> 3, h = bh & 7;
    int tid = threadIdx.x, wave = tid >> 6, lane = tid & 63;
    int l31 = lane & 31, l5 = lane >> 5;
    int col0 = b * NTOK + sl * 512 + wave * 128;
    const ushort_t* krow = qkv + (size_t)(256 + h * 32 + l31) * NCOLS + col0 + l5 * 8;
    const ushort_t* vrow = qkv + (size_t)(512 + h * 32 + l31) * NCOLS + col0 + l5 * 8;
    f32x16 acc;
#pragma unroll
    for (int i = 0; i < 16; i++) acc[i] = 0.f;
#pragma unroll
    for (int st = 0; st < 8; st++) {
        short8 kf = *(const short8*)(krow + st * 16);
        short8 vf = *(const short8*)(vrow + st * 16);   // v raw (B operand)
        short8 af;
#pragma unroll
        for (int j = 0; j < 8; j++) {
            float e = __expf(b2f((ushort_t)kf[j]));
            float t = e;
            t += __shfl_xor(t, 1);
            t += __shfl_xor(t, 2);
            t += __shfl_xor(t, 4);
            t += __shfl_xor(t, 8);
            t += __shfl_xor(t, 16);                     // sum over d (l31 group)
            af[j] = (short)f2b(__fdividef(e, t));
        }
        acc = __builtin_amdgcn_mfma_f32_32x32x16_bf16(af, vf, acc, 0, 0, 0);
    }
    __shared__ float red[4][1024];
#pragma unroll
    for (int r = 0; r < 16; r++) {
        int d = (r & 3) + 8 * (r >> 2) + 4 * l5;        // C/D row (m74/m101)
        red[wave][d * 32 + l31] = acc[r];
    }
    __syncthreads();
    int i0 = tid * 4;
#pragma unroll
    for (int i = 0; i < 4; i++) {
        int idx = i0 + i;
        float v = red[0][idx] + red[1][idx] + red[2][idx] + red[3][idx];
        atomicAdd(ctxbuf + (size_t)bh * 1024 + idx, v);
    }
}

// ---------------------------------------------------------------------------
// out[e][n] = sum_d ctx[d][e] * (exp(q[d][n])/S_q[d])  -> attT[token][256]
__global__ __launch_bounds__(256) void out_ker(const ushort_t* __restrict__ qkv,
                                               const float* __restrict__ ctxbuf,
                                               const float* __restrict__ qsums,
                                               ushort_t* __restrict__ attT) {
    int sl = blockIdx.x, bh = blockIdx.y;
    int b = bh >> 3, h = bh & 7;
    int tid = threadIdx.x, wave = tid >> 6, lane = tid & 63;
    int l31 = lane & 31, l5 = lane >> 5;
    __shared__ __align__(16) ushort_t ctxT[32 * 40];
    __shared__ __align__(16) ushort_t qT[256 * 40];
    __shared__ __align__(16) ushort_t obuf[4][32 * 40];

#pragma unroll
    for (int i = 0; i < 4; i++) {
        int idx = tid * 4 + i;
        int d = idx >> 5, e = idx & 31;
        ctxT[e * 40 + d] = f2b(ctxbuf[(size_t)bh * 1024 + idx]);  // k-norm already in ctx
    }
    __syncthreads();
    short8 a0 = *(const short8*)(ctxT + l31 * 40 + l5 * 8);
    short8 a1 = *(const short8*)(ctxT + l31 * 40 + 16 + l5 * 8);

    const ushort_t* qbase = qkv + (size_t)(h * 32) * NCOLS;
    int segbase = b * NTOK + sl * 512;
    int d = tid & 31, t8 = (tid >> 5) * 8;
    float sq = 1.f / qsums[(h * 32 + d) * 16 + b];     // per-thread row scale

    for (int nc = 0; nc < 2; nc++) {
        int gcol0 = segbase + nc * 256;
#pragma unroll
        for (int jj = 0; jj < 4; jj++) {
            int tok8 = jj * 64 + t8;
            short8 pk = *(const short8*)(qbase + (size_t)d * NCOLS + gcol0 + tok8);
#pragma unroll
            for (int j = 0; j < 8; j++)
                qT[(tok8 + j) * 40 + d] = f2b(__expf(b2f((ushort_t)pk[j])) * sq);
        }
        __syncthreads();
#pragma unroll
        for (int ti = 0; ti < 2; ti++) {
            int tok0 = (wave + ti * 4) * 32;
            f32x16 acc;
#pragma unroll
            for (int i = 0; i < 16; i++) acc[i] = 0.f;
            short8 b0 = *(const short8*)(qT + (size_t)(tok0 + l31) * 40 + l5 * 8);
            short8 b1 = *(const short8*)(qT + (size_t)(tok0 + l31) * 40 + 16 + l5 * 8);
            acc = __builtin_amdgcn_mfma_f32_32x32x16_bf16(a0, b0, acc, 0, 0, 0);
            acc = __builtin_amdgcn_mfma_f32_32x32x16_bf16(a1, b1, acc, 0, 0, 0);
#pragma unroll
            for (int r = 0; r < 16; r++) {
                int e = (r & 3) + 8 * (r >> 2) + 4 * l5;
                obuf[wave][l31 * 40 + e] = f2b(acc[r]);
            }
            __syncthreads();
            {
                int tok = lane >> 1, half = lane & 1;
                const ushort_t* srcp = &obuf[wave][tok * 40 + half * 16];
                short8 r0 = *(const short8*)srcp;
                short8 r1 = *(const short8*)(srcp + 8);
                size_t g = (size_t)(gcol0 + tok0 + tok) * 256 + h * 32 + half * 16;
                *(short8*)(attT + g) = r0;
                *(short8*)(attT + g + 8) = r1;
            }
            __syncthreads();
        }
        __syncthreads();
    }
}

// ---------------------------------------------------------------------------
extern "C" void kernel_launch(void* const* d_in, const int* in_sizes, int n_in,
                              void* d_out, int out_size, void* d_ws, size_t ws_size,
                              hipStream_t stream) {
    const float* x          = (const float*)d_in[0];
    const float* qkv_w      = (const float*)d_in[1];
    const float* qkv_gamma  = (const float*)d_in[2];
    const float* qkv_beta   = (const float*)d_in[3];
    const float* qkv_mean   = (const float*)d_in[4];
    const float* qkv_var    = (const float*)d_in[5];
    const float* proj_w     = (const float*)d_in[6];
    const float* proj_gamma = (const float*)d_in[7];
    const float* proj_beta  = (const float*)d_in[8];
    const float* proj_mean  = (const float*)d_in[9];
    const float* proj_var   = (const float*)d_in[10];

    ushort_t* wqb = (ushort_t*)d_ws;                 // 393,216 B
    ushort_t* wpb = wqb + 768 * 256;                 // 131,072 B
    ushort_t* xt  = wpb + 256 * 256;                 // 33.5 MB (also attT later)
    ushort_t* qkv = xt + (size_t)NCOLS * CIN;        // 100.7 MB
    float* out    = (float*)d_out;
    float* ctxbuf = (float*)d_out;                   // 512 KB scratch in d_out
    float* qsums  = ctxbuf + 131072;                 // 16 KB scratch in d_out

    cvt_w<<<1024, 256, 0, stream>>>(qkv_w, proj_w, wqb, wpb, ctxbuf);
    transpose_x<<<1024, 256, 0, stream>>>(x, xt);
    gemm128<<<dim3(512, 6), 256, 0, stream>>>(wqb, xt, qkv_gamma, qkv_beta,
                                              qkv_mean, qkv_var, qkv, nullptr, 0);
    qsum_ker<<<1024, 256, 0, stream>>>(qkv, qsums);
    ctx_ker<<<dim3(8, 128), 256, 0, stream>>>(qkv, ctxbuf);
    out_ker<<<dim3(8, 128), 256, 0, stream>>>(qkv, ctxbuf, qsums, xt);
    gemm128<<<dim3(512, 2), 256, 0, stream>>>(wpb, xt, proj_gamma, proj_beta,
                                              proj_mean, proj_var, nullptr, out, 1);
}